// Round 13
// baseline (289.270 us; speedup 1.0000x reference)
//
#include <hip/hip_runtime.h>
#include <hip/hip_bf16.h>

#define N_NODES 50000
#define N_PAD 50048        // rows padded so 64-row GEMM tiles can over-read
#define N_EDGES 800000
#define NBUCK 391          // ceil(50000/128) buckets of 128 dst nodes
#define CAP 4096           // pairBuf slots per bucket (expected 2046, >>6 sigma)

typedef short bf16x8 __attribute__((ext_vector_type(8)));
typedef float f32x4 __attribute__((ext_vector_type(4)));
typedef float floatx2 __attribute__((ext_vector_type(2)));

__device__ inline unsigned short f2b(float f) {
    union { float f; unsigned u; } v; v.f = f;
    unsigned r = v.u + 0x7FFF + ((v.u >> 16) & 1);   // RNE
    return (unsigned short)(r >> 16);
}
__device__ inline float b2f(unsigned short u) {
    union { unsigned u; float f; } v; v.u = ((unsigned)u) << 16; return v.f;
}

// ---------------------------------------------------------------------------
// Zero the 400-int bucketCount array (cheap 1-block kernel).
// ---------------------------------------------------------------------------
__global__ __launch_bounds__(512) void zero_bc(int* __restrict__ bucketCount) {
    int t = threadIdx.x;
    if (t < 400) bucketCount[t] = 0;
}

// ---------------------------------------------------------------------------
// Merged prep + edge partition. Blocks [0,196): scatter edges into
// fixed-capacity bucket regions; blocks [196, ...): cvt x->bf16+fp8, W->bf16.
// ---------------------------------------------------------------------------
#define XITEMS 1600000   // N_NODES*128/4
#define WITEMS 18432     // 73728/4
#define PB_EDGES 4096
#define SCAT_BLKS 196    // ceil(E / PB_EDGES)

__global__ __launch_bounds__(512) void prep_scatter(
        const float* __restrict__ x, unsigned short* __restrict__ xb,
        unsigned char* __restrict__ x8,
        const float* __restrict__ W1l, const float* __restrict__ W1r,
        const float* __restrict__ W2l, const float* __restrict__ W2r,
        const float* __restrict__ W3,
        unsigned short* __restrict__ w1lb, unsigned short* __restrict__ w1rb,
        unsigned short* __restrict__ w2lb, unsigned short* __restrict__ w2rb,
        unsigned short* __restrict__ w3b,
        const int* __restrict__ ei, int* __restrict__ bucketCount,
        unsigned long long* __restrict__ pairBuf) {
    __shared__ int hist[NBUCK];
    __shared__ int gbase[NBUCK];
    const int t = threadIdx.x;

    if (blockIdx.x < SCAT_BLKS) {
        const int E = N_EDGES;
        for (int i = t; i < NBUCK; i += 512) hist[i] = 0;
        __syncthreads();
        const int base = blockIdx.x * PB_EDGES;
        int srcv[8], dstv[8], lr[8], bk[8];
#pragma unroll
        for (int j = 0; j < 8; ++j) {
            int idx = base + j * 512 + t;
            if (idx < E) {
                srcv[j] = ei[idx];
                dstv[j] = ei[E + idx];
                bk[j] = dstv[j] >> 7;
                lr[j] = atomicAdd(&hist[bk[j]], 1);
            } else {
                bk[j] = -1; srcv[j] = 0; dstv[j] = 0; lr[j] = 0;
            }
        }
        __syncthreads();
        for (int i = t; i < NBUCK; i += 512) {
            int h = hist[i];
            if (h) gbase[i] = i * CAP + atomicAdd(&bucketCount[i], h);
        }
        __syncthreads();
#pragma unroll
        for (int j = 0; j < 8; ++j) {
            if (bk[j] >= 0) {
                int pos = gbase[bk[j]] + lr[j];
                pairBuf[pos] = ((unsigned long long)(unsigned)dstv[j] << 32) | (unsigned)srcv[j];
            }
        }
        return;
    }

    int gid = (blockIdx.x - SCAT_BLKS) * 512 + t;
    if (gid < XITEMS) {
        int idx = gid * 4;
        float4 v = *reinterpret_cast<const float4*>(x + idx);
        ushort4 o;
        o.x = f2b(v.x); o.y = f2b(v.y); o.z = f2b(v.z); o.w = f2b(v.w);
        *reinterpret_cast<ushort4*>(xb + idx) = o;
        unsigned r = __builtin_amdgcn_cvt_pk_fp8_f32(v.x, v.y, 0, false);
        r = __builtin_amdgcn_cvt_pk_fp8_f32(v.z, v.w, r, true);
        *reinterpret_cast<unsigned*>(x8 + idx) = r;
        return;
    }
    gid -= XITEMS;
    if (gid < WITEMS) {
        int idx = gid * 4;
        const float* s; unsigned short* o; int base;
        if      (idx < 16384) { s = W1l; o = w1lb; base = 0; }
        else if (idx < 32768) { s = W1r; o = w1rb; base = 16384; }
        else if (idx < 49152) { s = W2l; o = w2lb; base = 32768; }
        else if (idx < 65536) { s = W2r; o = w2rb; base = 49152; }
        else                  { s = W3;  o = w3b;  base = 65536; }
        int k = idx - base;
        float4 v = *reinterpret_cast<const float4*>(s + k);
        ushort4 w;
        w.x = f2b(v.x); w.y = f2b(v.y); w.z = f2b(v.z); w.w = f2b(v.w);
        *reinterpret_cast<ushort4*>(o + k) = w;
    }
}

// ---------------------------------------------------------------------------
// CSR pass 2: block per bucket -> offs + csr.
// ---------------------------------------------------------------------------
__global__ __launch_bounds__(512) void csr_sort(
        const unsigned long long* __restrict__ pairBuf,
        const int* __restrict__ bucketCount,
        int* __restrict__ offs, int* __restrict__ csr, int n) {
    __shared__ int sm[512];
    __shared__ int nb[128];
    __shared__ int nc[128];
    const int b = blockIdx.x, t = threadIdx.x;
    int v = (t < NBUCK) ? bucketCount[t] : 0;
    sm[t] = v;
    __syncthreads();
    for (int o = 1; o < 512; o <<= 1) {
        int a = (t >= o) ? sm[t - o] : 0;
        __syncthreads();
        sm[t] += a;
        __syncthreads();
    }
    const int count = bucketCount[b];
    const int base = sm[b] - count;       // exclusive prefix over buckets
    const int node0 = b << 7;
    const int nN = min(128, n - node0);
    if (t < 128) nc[t] = 0;
    __syncthreads();
    const unsigned long long* pb = pairBuf + (size_t)b * CAP;
    for (int i = t; i < count; i += 512) {
        int d = ((int)(pb[i] >> 32)) & 127;
        atomicAdd(&nc[d], 1);
    }
    __syncthreads();
    if (t < 128) sm[t] = nc[t];
    __syncthreads();
    for (int o = 1; o < 128; o <<= 1) {
        int a = 0;
        if (t < 128 && t >= o) a = sm[t - o];
        __syncthreads();
        if (t < 128) sm[t] += a;
        __syncthreads();
    }
    if (t < 128) nb[t] = base + sm[t] - nc[t];   // exclusive per-node base
    __syncthreads();
    if (t < nN) offs[node0 + t] = nb[t];
    if (b == NBUCK - 1 && t == 0) offs[n] = base + count;
    if (t < 128) nc[t] = 0;
    __syncthreads();
    for (int i = t; i < count; i += 512) {
        unsigned long long p = pb[i];
        int d = ((int)(p >> 32)) & 127;
        int r = atomicAdd(&nc[d], 1);
        csr[nb[d] + r] = (int)(p & 0xffffffffu);
    }
}

// ---------------------------------------------------------------------------
// Mean aggregation over fp8 rows (128 B). 8 lanes/node, uint4 (16B) loads:
// one wave-load instruction covers 8 rows (2x the 16-lane/uint2 scheme).
// Unroll x8 -> 8 rows in flight per group. f32 accum, bf16 out.
// ---------------------------------------------------------------------------
__device__ inline void acc16f(float* a, uint4 v) {
    floatx2 p;
    p = __builtin_amdgcn_cvt_pk_f32_fp8(v.x, false); a[0]  += p.x; a[1]  += p.y;
    p = __builtin_amdgcn_cvt_pk_f32_fp8(v.x, true);  a[2]  += p.x; a[3]  += p.y;
    p = __builtin_amdgcn_cvt_pk_f32_fp8(v.y, false); a[4]  += p.x; a[5]  += p.y;
    p = __builtin_amdgcn_cvt_pk_f32_fp8(v.y, true);  a[6]  += p.x; a[7]  += p.y;
    p = __builtin_amdgcn_cvt_pk_f32_fp8(v.z, false); a[8]  += p.x; a[9]  += p.y;
    p = __builtin_amdgcn_cvt_pk_f32_fp8(v.z, true);  a[10] += p.x; a[11] += p.y;
    p = __builtin_amdgcn_cvt_pk_f32_fp8(v.w, false); a[12] += p.x; a[13] += p.y;
    p = __builtin_amdgcn_cvt_pk_f32_fp8(v.w, true);  a[14] += p.x; a[15] += p.y;
}

__global__ __launch_bounds__(256, 6) void aggregate_fp8(
        const unsigned char* __restrict__ feat8, const int* __restrict__ offs,
        const int* __restrict__ csr, unsigned short* __restrict__ out, int n) {
    int grp = (blockIdx.x * 256 + threadIdx.x) >> 3;
    int l = threadIdx.x & 7;
    if (grp >= n) return;
    int beg = offs[grp], end = offs[grp + 1];
    int deg = end - beg;
    float acc[16] = {};
    for (int cb = 0; cb < deg; cb += 8) {
        int rem = deg - cb; if (rem > 8) rem = 8;
        int e = (cb + l < deg) ? csr[beg + cb + l] : 0;
        if (rem == 8) {
            uint4 v[8];
#pragma unroll
            for (int k = 0; k < 8; ++k) {
                int s = __shfl(e, k, 8);
                v[k] = *reinterpret_cast<const uint4*>(feat8 + (size_t)s * 128 + l * 16);
            }
#pragma unroll
            for (int k = 0; k < 8; ++k) acc16f(acc, v[k]);
        } else {
            for (int j = 0; j < rem; ++j) {
                int s = __shfl(e, j, 8);
                uint4 v = *reinterpret_cast<const uint4*>(feat8 + (size_t)s * 128 + l * 16);
                acc16f(acc, v);
            }
        }
    }
    float inv = deg > 0 ? 1.f / (float)deg : 0.f;
    uint4 o0, o1;
    o0.x = (unsigned)f2b(acc[0]  * inv) | ((unsigned)f2b(acc[1]  * inv) << 16);
    o0.y = (unsigned)f2b(acc[2]  * inv) | ((unsigned)f2b(acc[3]  * inv) << 16);
    o0.z = (unsigned)f2b(acc[4]  * inv) | ((unsigned)f2b(acc[5]  * inv) << 16);
    o0.w = (unsigned)f2b(acc[6]  * inv) | ((unsigned)f2b(acc[7]  * inv) << 16);
    o1.x = (unsigned)f2b(acc[8]  * inv) | ((unsigned)f2b(acc[9]  * inv) << 16);
    o1.y = (unsigned)f2b(acc[10] * inv) | ((unsigned)f2b(acc[11] * inv) << 16);
    o1.z = (unsigned)f2b(acc[12] * inv) | ((unsigned)f2b(acc[13] * inv) << 16);
    o1.w = (unsigned)f2b(acc[14] * inv) | ((unsigned)f2b(acc[15] * inv) << 16);
    uint4* dst = reinterpret_cast<uint4*>(out + (size_t)grp * 128 + l * 16);
    dst[0] = o0;
    dst[1] = o1;
}

// ---------------------------------------------------------------------------
// GEMM v4: 64 rows / 256 threads (4 waves). B (and W3) stationary in VGPRs;
// A staged coalesced -> swizzled LDS -> ds_read_b128 fragments.
// Epilogue routes C through a swizzled LDS tile (both variants):
//  !HEAD: read tile back coalesced, emit h1b (bf16 uint4) + h18 (fp8 uint2)
//   HEAD: tile = h2, second MFMA stage vs W3 -> f32 out.
// ---------------------------------------------------------------------------
template<bool HEAD>
__global__ __launch_bounds__(256, 2) void gemm_k(
        const unsigned short* __restrict__ A1, const unsigned short* __restrict__ B1,
        const unsigned short* __restrict__ A2, const unsigned short* __restrict__ B2,
        const float* __restrict__ bias,
        const unsigned short* __restrict__ W3, const float* __restrict__ b3,
        void* __restrict__ outP, unsigned char* __restrict__ fp8out, int M) {
    __shared__ char lds[49152];
    const int t = threadIdx.x;
    const int rowBase = blockIdx.x * 64;
    const int lane = t & 63, wv = t >> 6;
    const int ch = wv & 1, half = wv >> 1;
    const int fr = lane & 15, fq = lane >> 4;
    const int swz = (fr & 7) << 4;

    // ---- issue A staging loads (pre-swizzled source, linear LDS dest) ----
    const char* a1p = (const char*)(A1 + (size_t)rowBase * 128);
    const char* a2p = (const char*)(A2 + (size_t)rowBase * 128);
    uint4 st[8];
#pragma unroll
    for (int c = 0; c < 4; ++c) {
        int q = c * 4096 + t * 16;
        int src = q ^ (((q >> 8) & 7) << 4);
        st[c]     = *reinterpret_cast<const uint4*>(a1p + src);
        st[4 + c] = *reinterpret_cast<const uint4*>(a2p + src);
    }

    // ---- B fragments -> registers (once per wave; overlaps staging) ----
    bf16x8 bl[4][4], br[4][4];
#pragma unroll
    for (int nt = 0; nt < 4; ++nt) {
        const unsigned short* ql = B1 + (size_t)(ch * 64 + nt * 16 + fr) * 128 + fq * 8;
        const unsigned short* qr = B2 + (size_t)(ch * 64 + nt * 16 + fr) * 128 + fq * 8;
#pragma unroll
        for (int ks = 0; ks < 4; ++ks) {
            bl[nt][ks] = *reinterpret_cast<const bf16x8*>(ql + ks * 32);
            br[nt][ks] = *reinterpret_cast<const bf16x8*>(qr + ks * 32);
        }
    }
    bf16x8 w3f[2][4];
    if (HEAD) {
#pragma unroll
        for (int nt = 0; nt < 2; ++nt) {
            const unsigned short* q = W3 + (size_t)(ch * 32 + nt * 16 + fr) * 128 + fq * 8;
#pragma unroll
            for (int ks = 0; ks < 4; ++ks)
                w3f[nt][ks] = *reinterpret_cast<const bf16x8*>(q + ks * 32);
        }
    }

    // ---- write staged A to LDS ----
#pragma unroll
    for (int c = 0; c < 4; ++c) {
        *reinterpret_cast<uint4*>(lds + c * 4096 + t * 16)         = st[c];
        *reinterpret_cast<uint4*>(lds + 16384 + c * 4096 + t * 16) = st[4 + c];
    }
    __syncthreads();

    // ---- main GEMM: 2 row-tiles of 16 per wave; C -> swizzled LDS tile ----
#pragma unroll
    for (int tt = 0; tt < 2; ++tt) {
        const int rl = half * 32 + tt * 16 + fr;
        const int rb = rl * 256;
        f32x4 acc[4];
#pragma unroll
        for (int j = 0; j < 4; ++j) acc[j] = (f32x4){0.f, 0.f, 0.f, 0.f};
        bf16x8 a1[4], a2[4];
#pragma unroll
        for (int ks = 0; ks < 4; ++ks) {
            int off = rb + fq * 16 + ks * 64;
            a1[ks] = *reinterpret_cast<const bf16x8*>(lds + (off ^ swz));
            a2[ks] = *reinterpret_cast<const bf16x8*>(lds + 16384 + (off ^ swz));
        }
#pragma unroll
        for (int nt = 0; nt < 4; ++nt)
#pragma unroll
            for (int ks = 0; ks < 4; ++ks) {
                acc[nt] = __builtin_amdgcn_mfma_f32_16x16x32_bf16(a1[ks], bl[nt][ks], acc[nt], 0, 0, 0);
                acc[nt] = __builtin_amdgcn_mfma_f32_16x16x32_bf16(a2[ks], br[nt][ks], acc[nt], 0, 0, 0);
            }
#pragma unroll
        for (int i = 0; i < 4; ++i) {
            int rL = half * 32 + tt * 16 + fq * 4 + i;
#pragma unroll
            for (int nt = 0; nt < 4; ++nt) {
                int c = ch * 64 + nt * 16 + fr;
                float v = acc[nt][i] + bias[c];
                int off = (rL * 256 + c * 2) ^ ((rL & 7) << 4);
                *reinterpret_cast<unsigned short*>(lds + 32768 + off) = f2b(v > 0.f ? v : 0.f);
            }
        }
    }
    __syncthreads();

    if (!HEAD) {
        // ---- coalesced readback: h1b (bf16) + h18 (fp8) ----
        unsigned short* C = (unsigned short*)outP;
#pragma unroll
        for (int c4 = 0; c4 < 4; ++c4) {
            int g = c4 * 256 + t;          // chunk id 0..1023
            int rL = g >> 4, k = g & 15;
            int gm = rowBase + rL;
            if (gm >= M) continue;
            int off = (rL * 256 + k * 16) ^ ((rL & 7) << 4);
            uint4 v = *reinterpret_cast<const uint4*>(lds + 32768 + off);
            *reinterpret_cast<uint4*>(C + (size_t)gm * 128 + k * 8) = v;
            float f0 = b2f((unsigned short)(v.x & 0xffff)), f1 = b2f((unsigned short)(v.x >> 16));
            float f2 = b2f((unsigned short)(v.y & 0xffff)), f3 = b2f((unsigned short)(v.y >> 16));
            float f4 = b2f((unsigned short)(v.z & 0xffff)), f5 = b2f((unsigned short)(v.z >> 16));
            float f6 = b2f((unsigned short)(v.w & 0xffff)), f7 = b2f((unsigned short)(v.w >> 16));
            uint2 o;
            o.x = __builtin_amdgcn_cvt_pk_fp8_f32(f0, f1, 0, false);
            o.x = __builtin_amdgcn_cvt_pk_fp8_f32(f2, f3, o.x, true);
            o.y = __builtin_amdgcn_cvt_pk_fp8_f32(f4, f5, 0, false);
            o.y = __builtin_amdgcn_cvt_pk_fp8_f32(f6, f7, o.y, true);
            *reinterpret_cast<uint2*>(fp8out + (size_t)gm * 128 + k * 8) = o;
        }
    } else {
        // ---- head: out = relu(h2 @ W3^T + b3), 64 cols, f32 ----
        float* out = (float*)outP;
#pragma unroll
        for (int tt = 0; tt < 2; ++tt) {
            const int rl = half * 32 + tt * 16 + fr;
            const int rb = rl * 256;
            bf16x8 a3[4];
#pragma unroll
            for (int ks = 0; ks < 4; ++ks) {
                int off = rb + fq * 16 + ks * 64;
                a3[ks] = *reinterpret_cast<const bf16x8*>(lds + 32768 + (off ^ swz));
            }
            f32x4 acc3[2];
#pragma unroll
            for (int j = 0; j < 2; ++j) acc3[j] = (f32x4){0.f, 0.f, 0.f, 0.f};
#pragma unroll
            for (int nt = 0; nt < 2; ++nt)
#pragma unroll
                for (int ks = 0; ks < 4; ++ks)
                    acc3[nt] = __builtin_amdgcn_mfma_f32_16x16x32_bf16(a3[ks], w3f[nt][ks], acc3[nt], 0, 0, 0);
#pragma unroll
            for (int i = 0; i < 4; ++i) {
                int gm = rowBase + half * 32 + tt * 16 + fq * 4 + i;
                if (gm >= M) continue;
#pragma unroll
                for (int nt = 0; nt < 2; ++nt) {
                    int c = ch * 32 + nt * 16 + fr;
                    float v = acc3[nt][i] + b3[c];
                    out[(size_t)gm * 64 + c] = v > 0.f ? v : 0.f;
                }
            }
        }
    }
}

// ---------------------------------------------------------------------------
extern "C" void kernel_launch(void* const* d_in, const int* in_sizes, int n_in,
                              void* d_out, int out_size, void* d_ws, size_t ws_size,
                              hipStream_t stream) {
    const float* x   = (const float*)d_in[0];
    const int*   ei  = (const int*)d_in[1];
    const float* W1l = (const float*)d_in[2];
    const float* b1l = (const float*)d_in[3];
    const float* W1r = (const float*)d_in[4];
    const float* W2l = (const float*)d_in[5];
    const float* b2l = (const float*)d_in[6];
    const float* W2r = (const float*)d_in[7];
    const float* W3  = (const float*)d_in[8];
    const float* b3  = (const float*)d_in[9];
    float* out = (float*)d_out;

    const int NN = N_NODES, E = N_EDGES;

    char* base = (char*)d_ws;
    // padded feature buffers: N_PAD rows x 256 B = 12,812,288 each
    unsigned short* xb    = (unsigned short*)(base + 0);
    unsigned short* h1b   = (unsigned short*)(base + 12812288);
    unsigned short* meanb = (unsigned short*)(base + 25624576);
    unsigned char*  x8    = (unsigned char*) (base + 38436864);  // 6,400,000
    unsigned char*  h18   = (unsigned char*) (base + 44836864);  // 6,400,000
    unsigned short* w1lb  = (unsigned short*)(base + 51236864);
    unsigned short* w1rb  = (unsigned short*)(base + 51269632);
    unsigned short* w2lb  = (unsigned short*)(base + 51302400);
    unsigned short* w2rb  = (unsigned short*)(base + 51335168);
    unsigned short* w3b   = (unsigned short*)(base + 51367936);  // 16,384
    int* offs             = (int*)(base + 51384320);             // 200,064
    int* bucketCount      = (int*)(base + 51584384);             // 1,600 (+pad)
    int* csr              = (int*)(base + 51586048);             // 3,200,000
    unsigned long long* pairBuf = (unsigned long long*)(base + 54786048); // 12,812,288

    zero_bc<<<1, 512, 0, stream>>>(bucketCount);

    const int PREP_BLKS = (XITEMS + WITEMS + 511) / 512;   // 3161
    prep_scatter<<<SCAT_BLKS + PREP_BLKS, 512, 0, stream>>>(
        x, xb, x8, W1l, W1r, W2l, W2r, W3, w1lb, w1rb, w2lb, w2rb, w3b,
        ei, bucketCount, pairBuf);

    csr_sort<<<NBUCK, 512, 0, stream>>>(pairBuf, bucketCount, offs, csr, NN);

    const int AGG_BLK = (NN * 8 + 255) / 256;    // 1563
    const int GB64 = (NN + 63) / 64;             // 782

    // Layer 1 (gemm writes h1b bf16 + h18 fp8 in one pass)
    aggregate_fp8<<<AGG_BLK, 256, 0, stream>>>(x8, offs, csr, meanb, NN);
    gemm_k<false><<<GB64, 256, 0, stream>>>(meanb, w1lb, xb, w1rb, b1l,
                                            nullptr, nullptr, h1b, h18, NN);

    // Layer 2 + head
    aggregate_fp8<<<AGG_BLK, 256, 0, stream>>>(h18, offs, csr, meanb, NN);
    gemm_k<true><<<GB64, 256, 0, stream>>>(meanb, w2lb, h1b, w2rb, b2l,
                                           w3b, b3, out, nullptr, NN);
}

// Round 14
// 124.802 us; speedup vs baseline: 2.3178x; 2.3178x over previous
//
#include <hip/hip_runtime.h>
#include <hip/hip_bf16.h>

#define N_NODES 50000
#define N_PAD 50048        // rows padded so 64-row GEMM tiles can over-read
#define N_EDGES 800000
#define NBUCK 391          // ceil(50000/128) buckets of 128 dst nodes
#define CAP 4096           // pairBuf slots per bucket (expected 2046, >>6 sigma)

typedef short bf16x8 __attribute__((ext_vector_type(8)));
typedef float f32x4 __attribute__((ext_vector_type(4)));
typedef float floatx2 __attribute__((ext_vector_type(2)));

__device__ inline unsigned short f2b(float f) {
    union { float f; unsigned u; } v; v.f = f;
    unsigned r = v.u + 0x7FFF + ((v.u >> 16) & 1);   // RNE
    return (unsigned short)(r >> 16);
}
__device__ inline float b2f(unsigned short u) {
    union { unsigned u; float f; } v; v.u = ((unsigned)u) << 16; return v.f;
}

// ---------------------------------------------------------------------------
// Zero the 400-int bucketCount array (cheap 1-block kernel).
// ---------------------------------------------------------------------------
__global__ __launch_bounds__(512) void zero_bc(int* __restrict__ bucketCount) {
    int t = threadIdx.x;
    if (t < 400) bucketCount[t] = 0;
}

// ---------------------------------------------------------------------------
// Merged prep + edge partition. Blocks [0,196): scatter edges into
// fixed-capacity bucket regions; blocks [196, ...): cvt x->bf16+fp8, W->bf16.
// ---------------------------------------------------------------------------
#define XITEMS 1600000   // N_NODES*128/4
#define WITEMS 18432     // 73728/4
#define PB_EDGES 4096
#define SCAT_BLKS 196    // ceil(E / PB_EDGES)

__global__ __launch_bounds__(512) void prep_scatter(
        const float* __restrict__ x, unsigned short* __restrict__ xb,
        unsigned char* __restrict__ x8,
        const float* __restrict__ W1l, const float* __restrict__ W1r,
        const float* __restrict__ W2l, const float* __restrict__ W2r,
        const float* __restrict__ W3,
        unsigned short* __restrict__ w1lb, unsigned short* __restrict__ w1rb,
        unsigned short* __restrict__ w2lb, unsigned short* __restrict__ w2rb,
        unsigned short* __restrict__ w3b,
        const int* __restrict__ ei, int* __restrict__ bucketCount,
        unsigned long long* __restrict__ pairBuf) {
    __shared__ int hist[NBUCK];
    __shared__ int gbase[NBUCK];
    const int t = threadIdx.x;

    if (blockIdx.x < SCAT_BLKS) {
        const int E = N_EDGES;
        for (int i = t; i < NBUCK; i += 512) hist[i] = 0;
        __syncthreads();
        const int base = blockIdx.x * PB_EDGES;
        int srcv[8], dstv[8], lr[8], bk[8];
#pragma unroll
        for (int j = 0; j < 8; ++j) {
            int idx = base + j * 512 + t;
            if (idx < E) {
                srcv[j] = ei[idx];
                dstv[j] = ei[E + idx];
                bk[j] = dstv[j] >> 7;
                lr[j] = atomicAdd(&hist[bk[j]], 1);
            } else {
                bk[j] = -1; srcv[j] = 0; dstv[j] = 0; lr[j] = 0;
            }
        }
        __syncthreads();
        for (int i = t; i < NBUCK; i += 512) {
            int h = hist[i];
            if (h) gbase[i] = i * CAP + atomicAdd(&bucketCount[i], h);
        }
        __syncthreads();
#pragma unroll
        for (int j = 0; j < 8; ++j) {
            if (bk[j] >= 0) {
                int pos = gbase[bk[j]] + lr[j];
                pairBuf[pos] = ((unsigned long long)(unsigned)dstv[j] << 32) | (unsigned)srcv[j];
            }
        }
        return;
    }

    int gid = (blockIdx.x - SCAT_BLKS) * 512 + t;
    if (gid < XITEMS) {
        int idx = gid * 4;
        float4 v = *reinterpret_cast<const float4*>(x + idx);
        ushort4 o;
        o.x = f2b(v.x); o.y = f2b(v.y); o.z = f2b(v.z); o.w = f2b(v.w);
        *reinterpret_cast<ushort4*>(xb + idx) = o;
        unsigned r = __builtin_amdgcn_cvt_pk_fp8_f32(v.x, v.y, 0, false);
        r = __builtin_amdgcn_cvt_pk_fp8_f32(v.z, v.w, r, true);
        *reinterpret_cast<unsigned*>(x8 + idx) = r;
        return;
    }
    gid -= XITEMS;
    if (gid < WITEMS) {
        int idx = gid * 4;
        const float* s; unsigned short* o; int base;
        if      (idx < 16384) { s = W1l; o = w1lb; base = 0; }
        else if (idx < 32768) { s = W1r; o = w1rb; base = 16384; }
        else if (idx < 49152) { s = W2l; o = w2lb; base = 32768; }
        else if (idx < 65536) { s = W2r; o = w2rb; base = 49152; }
        else                  { s = W3;  o = w3b;  base = 65536; }
        int k = idx - base;
        float4 v = *reinterpret_cast<const float4*>(s + k);
        ushort4 w;
        w.x = f2b(v.x); w.y = f2b(v.y); w.z = f2b(v.z); w.w = f2b(v.w);
        *reinterpret_cast<ushort4*>(o + k) = w;
    }
}

// ---------------------------------------------------------------------------
// CSR pass 2: block per bucket -> offs + csr.
// ---------------------------------------------------------------------------
__global__ __launch_bounds__(512) void csr_sort(
        const unsigned long long* __restrict__ pairBuf,
        const int* __restrict__ bucketCount,
        int* __restrict__ offs, int* __restrict__ csr, int n) {
    __shared__ int sm[512];
    __shared__ int nb[128];
    __shared__ int nc[128];
    const int b = blockIdx.x, t = threadIdx.x;
    int v = (t < NBUCK) ? bucketCount[t] : 0;
    sm[t] = v;
    __syncthreads();
    for (int o = 1; o < 512; o <<= 1) {
        int a = (t >= o) ? sm[t - o] : 0;
        __syncthreads();
        sm[t] += a;
        __syncthreads();
    }
    const int count = bucketCount[b];
    const int base = sm[b] - count;       // exclusive prefix over buckets
    const int node0 = b << 7;
    const int nN = min(128, n - node0);
    if (t < 128) nc[t] = 0;
    __syncthreads();
    const unsigned long long* pb = pairBuf + (size_t)b * CAP;
    for (int i = t; i < count; i += 512) {
        int d = ((int)(pb[i] >> 32)) & 127;
        atomicAdd(&nc[d], 1);
    }
    __syncthreads();
    if (t < 128) sm[t] = nc[t];
    __syncthreads();
    for (int o = 1; o < 128; o <<= 1) {
        int a = 0;
        if (t < 128 && t >= o) a = sm[t - o];
        __syncthreads();
        if (t < 128) sm[t] += a;
        __syncthreads();
    }
    if (t < 128) nb[t] = base + sm[t] - nc[t];   // exclusive per-node base
    __syncthreads();
    if (t < nN) offs[node0 + t] = nb[t];
    if (b == NBUCK - 1 && t == 0) offs[n] = base + count;
    if (t < 128) nc[t] = 0;
    __syncthreads();
    for (int i = t; i < count; i += 512) {
        unsigned long long p = pb[i];
        int d = ((int)(p >> 32)) & 127;
        int r = atomicAdd(&nc[d], 1);
        csr[nb[d] + r] = (int)(p & 0xffffffffu);
    }
}

// ---------------------------------------------------------------------------
// Mean aggregation over fp8 rows (128 B). 8 lanes/node, uint4 (16B) loads:
// one wave-load covers 8 rows. Unroll x4 (v[4] = 16 VGPR in flight) under a
// 128-VGPR cap -- r13's unroll x8 at (256,6) spilled to scratch (188 MB).
// ---------------------------------------------------------------------------
__device__ inline void acc16f(float* a, uint4 v) {
    floatx2 p;
    p = __builtin_amdgcn_cvt_pk_f32_fp8(v.x, false); a[0]  += p.x; a[1]  += p.y;
    p = __builtin_amdgcn_cvt_pk_f32_fp8(v.x, true);  a[2]  += p.x; a[3]  += p.y;
    p = __builtin_amdgcn_cvt_pk_f32_fp8(v.y, false); a[4]  += p.x; a[5]  += p.y;
    p = __builtin_amdgcn_cvt_pk_f32_fp8(v.y, true);  a[6]  += p.x; a[7]  += p.y;
    p = __builtin_amdgcn_cvt_pk_f32_fp8(v.z, false); a[8]  += p.x; a[9]  += p.y;
    p = __builtin_amdgcn_cvt_pk_f32_fp8(v.z, true);  a[10] += p.x; a[11] += p.y;
    p = __builtin_amdgcn_cvt_pk_f32_fp8(v.w, false); a[12] += p.x; a[13] += p.y;
    p = __builtin_amdgcn_cvt_pk_f32_fp8(v.w, true);  a[14] += p.x; a[15] += p.y;
}

__global__ __launch_bounds__(256, 4) void aggregate_fp8(
        const unsigned char* __restrict__ feat8, const int* __restrict__ offs,
        const int* __restrict__ csr, unsigned short* __restrict__ out, int n) {
    int grp = (blockIdx.x * 256 + threadIdx.x) >> 3;
    int l = threadIdx.x & 7;
    if (grp >= n) return;
    int beg = offs[grp], end = offs[grp + 1];
    int deg = end - beg;
    float acc[16] = {};
    for (int cb = 0; cb < deg; cb += 8) {
        int rem = deg - cb; if (rem > 8) rem = 8;
        int e = (cb + l < deg) ? csr[beg + cb + l] : 0;
        int j = 0;
        for (; j + 3 < rem; j += 4) {
            uint4 v0, v1, v2, v3;
            {
                int s0 = __shfl(e, j + 0, 8);
                int s1 = __shfl(e, j + 1, 8);
                int s2 = __shfl(e, j + 2, 8);
                int s3 = __shfl(e, j + 3, 8);
                v0 = *reinterpret_cast<const uint4*>(feat8 + (size_t)s0 * 128 + l * 16);
                v1 = *reinterpret_cast<const uint4*>(feat8 + (size_t)s1 * 128 + l * 16);
                v2 = *reinterpret_cast<const uint4*>(feat8 + (size_t)s2 * 128 + l * 16);
                v3 = *reinterpret_cast<const uint4*>(feat8 + (size_t)s3 * 128 + l * 16);
            }
            acc16f(acc, v0); acc16f(acc, v1); acc16f(acc, v2); acc16f(acc, v3);
        }
        for (; j < rem; ++j) {
            int s = __shfl(e, j, 8);
            uint4 v = *reinterpret_cast<const uint4*>(feat8 + (size_t)s * 128 + l * 16);
            acc16f(acc, v);
        }
    }
    float inv = deg > 0 ? 1.f / (float)deg : 0.f;
    uint4 o0, o1;
    o0.x = (unsigned)f2b(acc[0]  * inv) | ((unsigned)f2b(acc[1]  * inv) << 16);
    o0.y = (unsigned)f2b(acc[2]  * inv) | ((unsigned)f2b(acc[3]  * inv) << 16);
    o0.z = (unsigned)f2b(acc[4]  * inv) | ((unsigned)f2b(acc[5]  * inv) << 16);
    o0.w = (unsigned)f2b(acc[6]  * inv) | ((unsigned)f2b(acc[7]  * inv) << 16);
    o1.x = (unsigned)f2b(acc[8]  * inv) | ((unsigned)f2b(acc[9]  * inv) << 16);
    o1.y = (unsigned)f2b(acc[10] * inv) | ((unsigned)f2b(acc[11] * inv) << 16);
    o1.z = (unsigned)f2b(acc[12] * inv) | ((unsigned)f2b(acc[13] * inv) << 16);
    o1.w = (unsigned)f2b(acc[14] * inv) | ((unsigned)f2b(acc[15] * inv) << 16);
    uint4* dst = reinterpret_cast<uint4*>(out + (size_t)grp * 128 + l * 16);
    dst[0] = o0;
    dst[1] = o1;
}

// ---------------------------------------------------------------------------
// GEMM v4: 64 rows / 256 threads (4 waves). B (and W3) stationary in VGPRs;
// A staged coalesced -> swizzled LDS -> ds_read_b128 fragments.
// Epilogue routes C through a swizzled LDS tile (both variants):
//  !HEAD: read tile back coalesced, emit h1b (bf16 uint4) + h18 (fp8 uint2)
//   HEAD: tile = h2, second MFMA stage vs W3 -> f32 out.
// ---------------------------------------------------------------------------
template<bool HEAD>
__global__ __launch_bounds__(256, 2) void gemm_k(
        const unsigned short* __restrict__ A1, const unsigned short* __restrict__ B1,
        const unsigned short* __restrict__ A2, const unsigned short* __restrict__ B2,
        const float* __restrict__ bias,
        const unsigned short* __restrict__ W3, const float* __restrict__ b3,
        void* __restrict__ outP, unsigned char* __restrict__ fp8out, int M) {
    __shared__ char lds[49152];
    const int t = threadIdx.x;
    const int rowBase = blockIdx.x * 64;
    const int lane = t & 63, wv = t >> 6;
    const int ch = wv & 1, half = wv >> 1;
    const int fr = lane & 15, fq = lane >> 4;
    const int swz = (fr & 7) << 4;

    // ---- issue A staging loads (pre-swizzled source, linear LDS dest) ----
    const char* a1p = (const char*)(A1 + (size_t)rowBase * 128);
    const char* a2p = (const char*)(A2 + (size_t)rowBase * 128);
    uint4 st[8];
#pragma unroll
    for (int c = 0; c < 4; ++c) {
        int q = c * 4096 + t * 16;
        int src = q ^ (((q >> 8) & 7) << 4);
        st[c]     = *reinterpret_cast<const uint4*>(a1p + src);
        st[4 + c] = *reinterpret_cast<const uint4*>(a2p + src);
    }

    // ---- B fragments -> registers (once per wave; overlaps staging) ----
    bf16x8 bl[4][4], br[4][4];
#pragma unroll
    for (int nt = 0; nt < 4; ++nt) {
        const unsigned short* ql = B1 + (size_t)(ch * 64 + nt * 16 + fr) * 128 + fq * 8;
        const unsigned short* qr = B2 + (size_t)(ch * 64 + nt * 16 + fr) * 128 + fq * 8;
#pragma unroll
        for (int ks = 0; ks < 4; ++ks) {
            bl[nt][ks] = *reinterpret_cast<const bf16x8*>(ql + ks * 32);
            br[nt][ks] = *reinterpret_cast<const bf16x8*>(qr + ks * 32);
        }
    }
    bf16x8 w3f[2][4];
    if (HEAD) {
#pragma unroll
        for (int nt = 0; nt < 2; ++nt) {
            const unsigned short* q = W3 + (size_t)(ch * 32 + nt * 16 + fr) * 128 + fq * 8;
#pragma unroll
            for (int ks = 0; ks < 4; ++ks)
                w3f[nt][ks] = *reinterpret_cast<const bf16x8*>(q + ks * 32);
        }
    }

    // ---- write staged A to LDS ----
#pragma unroll
    for (int c = 0; c < 4; ++c) {
        *reinterpret_cast<uint4*>(lds + c * 4096 + t * 16)         = st[c];
        *reinterpret_cast<uint4*>(lds + 16384 + c * 4096 + t * 16) = st[4 + c];
    }
    __syncthreads();

    // ---- main GEMM: 2 row-tiles of 16 per wave; C -> swizzled LDS tile ----
#pragma unroll
    for (int tt = 0; tt < 2; ++tt) {
        const int rl = half * 32 + tt * 16 + fr;
        const int rb = rl * 256;
        f32x4 acc[4];
#pragma unroll
        for (int j = 0; j < 4; ++j) acc[j] = (f32x4){0.f, 0.f, 0.f, 0.f};
        bf16x8 a1[4], a2[4];
#pragma unroll
        for (int ks = 0; ks < 4; ++ks) {
            int off = rb + fq * 16 + ks * 64;
            a1[ks] = *reinterpret_cast<const bf16x8*>(lds + (off ^ swz));
            a2[ks] = *reinterpret_cast<const bf16x8*>(lds + 16384 + (off ^ swz));
        }
#pragma unroll
        for (int nt = 0; nt < 4; ++nt)
#pragma unroll
            for (int ks = 0; ks < 4; ++ks) {
                acc[nt] = __builtin_amdgcn_mfma_f32_16x16x32_bf16(a1[ks], bl[nt][ks], acc[nt], 0, 0, 0);
                acc[nt] = __builtin_amdgcn_mfma_f32_16x16x32_bf16(a2[ks], br[nt][ks], acc[nt], 0, 0, 0);
            }
#pragma unroll
        for (int i = 0; i < 4; ++i) {
            int rL = half * 32 + tt * 16 + fq * 4 + i;
#pragma unroll
            for (int nt = 0; nt < 4; ++nt) {
                int c = ch * 64 + nt * 16 + fr;
                float v = acc[nt][i] + bias[c];
                int off = (rL * 256 + c * 2) ^ ((rL & 7) << 4);
                *reinterpret_cast<unsigned short*>(lds + 32768 + off) = f2b(v > 0.f ? v : 0.f);
            }
        }
    }
    __syncthreads();

    if (!HEAD) {
        // ---- coalesced readback: h1b (bf16) + h18 (fp8) ----
        unsigned short* C = (unsigned short*)outP;
#pragma unroll
        for (int c4 = 0; c4 < 4; ++c4) {
            int g = c4 * 256 + t;          // chunk id 0..1023
            int rL = g >> 4, k = g & 15;
            int gm = rowBase + rL;
            if (gm >= M) continue;
            int off = (rL * 256 + k * 16) ^ ((rL & 7) << 4);
            uint4 v = *reinterpret_cast<const uint4*>(lds + 32768 + off);
            *reinterpret_cast<uint4*>(C + (size_t)gm * 128 + k * 8) = v;
            float f0 = b2f((unsigned short)(v.x & 0xffff)), f1 = b2f((unsigned short)(v.x >> 16));
            float f2 = b2f((unsigned short)(v.y & 0xffff)), f3 = b2f((unsigned short)(v.y >> 16));
            float f4 = b2f((unsigned short)(v.z & 0xffff)), f5 = b2f((unsigned short)(v.z >> 16));
            float f6 = b2f((unsigned short)(v.w & 0xffff)), f7 = b2f((unsigned short)(v.w >> 16));
            uint2 o;
            o.x = __builtin_amdgcn_cvt_pk_fp8_f32(f0, f1, 0, false);
            o.x = __builtin_amdgcn_cvt_pk_fp8_f32(f2, f3, o.x, true);
            o.y = __builtin_amdgcn_cvt_pk_fp8_f32(f4, f5, 0, false);
            o.y = __builtin_amdgcn_cvt_pk_fp8_f32(f6, f7, o.y, true);
            *reinterpret_cast<uint2*>(fp8out + (size_t)gm * 128 + k * 8) = o;
        }
    } else {
        // ---- head: out = relu(h2 @ W3^T + b3), 64 cols, f32 ----
        float* out = (float*)outP;
#pragma unroll
        for (int tt = 0; tt < 2; ++tt) {
            const int rl = half * 32 + tt * 16 + fr;
            const int rb = rl * 256;
            bf16x8 a3[4];
#pragma unroll
            for (int ks = 0; ks < 4; ++ks) {
                int off = rb + fq * 16 + ks * 64;
                a3[ks] = *reinterpret_cast<const bf16x8*>(lds + 32768 + (off ^ swz));
            }
            f32x4 acc3[2];
#pragma unroll
            for (int j = 0; j < 2; ++j) acc3[j] = (f32x4){0.f, 0.f, 0.f, 0.f};
#pragma unroll
            for (int nt = 0; nt < 2; ++nt)
#pragma unroll
                for (int ks = 0; ks < 4; ++ks)
                    acc3[nt] = __builtin_amdgcn_mfma_f32_16x16x32_bf16(a3[ks], w3f[nt][ks], acc3[nt], 0, 0, 0);
#pragma unroll
            for (int i = 0; i < 4; ++i) {
                int gm = rowBase + half * 32 + tt * 16 + fq * 4 + i;
                if (gm >= M) continue;
#pragma unroll
                for (int nt = 0; nt < 2; ++nt) {
                    int c = ch * 32 + nt * 16 + fr;
                    float v = acc3[nt][i] + b3[c];
                    out[(size_t)gm * 64 + c] = v > 0.f ? v : 0.f;
                }
            }
        }
    }
}

// ---------------------------------------------------------------------------
extern "C" void kernel_launch(void* const* d_in, const int* in_sizes, int n_in,
                              void* d_out, int out_size, void* d_ws, size_t ws_size,
                              hipStream_t stream) {
    const float* x   = (const float*)d_in[0];
    const int*   ei  = (const int*)d_in[1];
    const float* W1l = (const float*)d_in[2];
    const float* b1l = (const float*)d_in[3];
    const float* W1r = (const float*)d_in[4];
    const float* W2l = (const float*)d_in[5];
    const float* b2l = (const float*)d_in[6];
    const float* W2r = (const float*)d_in[7];
    const float* W3  = (const float*)d_in[8];
    const float* b3  = (const float*)d_in[9];
    float* out = (float*)d_out;

    const int NN = N_NODES, E = N_EDGES;

    char* base = (char*)d_ws;
    // padded feature buffers: N_PAD rows x 256 B = 12,812,288 each
    unsigned short* xb    = (unsigned short*)(base + 0);
    unsigned short* h1b   = (unsigned short*)(base + 12812288);
    unsigned short* meanb = (unsigned short*)(base + 25624576);
    unsigned char*  x8    = (unsigned char*) (base + 38436864);  // 6,400,000
    unsigned char*  h18   = (unsigned char*) (base + 44836864);  // 6,400,000
    unsigned short* w1lb  = (unsigned short*)(base + 51236864);
    unsigned short* w1rb  = (unsigned short*)(base + 51269632);
    unsigned short* w2lb  = (unsigned short*)(base + 51302400);
    unsigned short* w2rb  = (unsigned short*)(base + 51335168);
    unsigned short* w3b   = (unsigned short*)(base + 51367936);  // 16,384
    int* offs             = (int*)(base + 51384320);             // 200,064
    int* bucketCount      = (int*)(base + 51584384);             // 1,600 (+pad)
    int* csr              = (int*)(base + 51586048);             // 3,200,000
    unsigned long long* pairBuf = (unsigned long long*)(base + 54786048); // 12,812,288

    zero_bc<<<1, 512, 0, stream>>>(bucketCount);

    const int PREP_BLKS = (XITEMS + WITEMS + 511) / 512;   // 3161
    prep_scatter<<<SCAT_BLKS + PREP_BLKS, 512, 0, stream>>>(
        x, xb, x8, W1l, W1r, W2l, W2r, W3, w1lb, w1rb, w2lb, w2rb, w3b,
        ei, bucketCount, pairBuf);

    csr_sort<<<NBUCK, 512, 0, stream>>>(pairBuf, bucketCount, offs, csr, NN);

    const int AGG_BLK = (NN * 8 + 255) / 256;    // 1563
    const int GB64 = (NN + 63) / 64;             // 782

    // Layer 1 (gemm writes h1b bf16 + h18 fp8 in one pass)
    aggregate_fp8<<<AGG_BLK, 256, 0, stream>>>(x8, offs, csr, meanb, NN);
    gemm_k<false><<<GB64, 256, 0, stream>>>(meanb, w1lb, xb, w1rb, b1l,
                                            nullptr, nullptr, h1b, h18, NN);

    // Layer 2 + head
    aggregate_fp8<<<AGG_BLK, 256, 0, stream>>>(h18, offs, csr, meanb, NN);
    gemm_k<true><<<GB64, 256, 0, stream>>>(meanb, w2lb, h1b, w2rb, b2l,
                                           w3b, b3, out, nullptr, NN);
}